// Round 8
// baseline (209.854 us; speedup 1.0000x reference)
//
#include <hip/hip_runtime.h>
#include <math.h>

#define TOKENS 16384
#define DIM    2048
#define NE     64
#define TB     32            // tokens per block (one 32-row MFMA tile)
#define KG     8             // k-split across the block's 8 waves
#define BK     128           // k staged per step (32 rows x 128 f32 = 16 KB buffer)
#define NSTEP  (DIM / BK)    // 16 steps; per wave per step: 1 chunk of 16 k

typedef _Float16 f16x8 __attribute__((ext_vector_type(8)));
typedef float    f32x16 __attribute__((ext_vector_type(16)));

// ---------- Single-kernel router: raw-W split-f16 MFMA GEMM + top-2 + softmax ----------
// R8 change: wpack kernel ELIMINATED. Each wave loads its own raw fp32 W chunk
// (4 float4/lane/step, same VMEM op count as the old packed loads -> identical
// vmcnt bookkeeping) and does the split-f16 conversion in COMP, where the ~60
// extra VALU/chunk hide under the ~3200-cy/step HBM service budget. W is 512 KB
// -> L2-resident after first touch; lane mapping (e = eg*32+(lane&31),
// k0 = C*16+(lane>>5)*8) is exactly what wpack produced, so math is bit-identical.
// Saves the wpack dispatch + inter-launch dependency bubble; d_ws now unused.
// Phase rotation (R7) removed: measured null.
// Structure = verified R3: 4 stage bufs, depth-3 prefetch, counted vmcnt,
// raw s_barrier, swizzled staging (slot = g ^ (row&7)) on both sides.
__global__ __launch_bounds__(512, 4) void router_kernel(const float* __restrict__ x,
                                                        const float* __restrict__ W,
                                                        const float* __restrict__ b,
                                                        float* __restrict__ out) {
    __shared__ __align__(16) float lds[16384];   // 64 KB: 4x16KB stage bufs, reused as 8 zones

    const int tid  = threadIdx.x;
    const int kg   = tid >> 6;
    const int lane = tid & 63;
    const int t0   = blockIdx.x * TB;
    const int m    = lane & 31;        // token row within tile (frag row)
    const int ko   = lane >> 5;        // k-octet half

    const float* xbase = x + (size_t)t0 * DIM;
    // per-lane W base: expert row (lane&31), k-octet (lane>>5)*8; eg1 adds 32 rows
    const float* wbase = W + (size_t)(lane & 31) * DIM + (lane >> 5) * 8;

    f32x16 acc0, acc1;
    #pragma unroll
    for (int i = 0; i < 16; ++i) { acc0[i] = 0.0f; acc1[i] = 0.0f; }

    float4 ws[2][4];   // raw W staging: [slot][eg0 q0, eg0 q1, eg1 q0, eg1 q1]

    // swizzled ds_read byte offsets within a 16KB buffer (constant across steps)
    const int gq  = kg * 4 + ko * 2;
    const int ro0 = m * 512 + (((gq + 0) ^ (m & 7)) << 4);
    const int ro1 = m * 512 + (((gq + 1) ^ (m & 7)) << 4);

    // stage step S: wave kg stages rows 4kg..4kg+3 (2 instrs, 2 rows = 1KB each)
#define STAGE(S) do {                                                            \
        _Pragma("unroll")                                                        \
        for (int i_ = 0; i_ < 2; ++i_) {                                         \
            const int rp_ = 4 * kg + 2 * i_;                                     \
            const int r_  = rp_ + (lane >> 5);                                   \
            const int sg_ = (lane & 31) ^ (r_ & 7);                              \
            const float* src_ = xbase + (size_t)r_ * DIM + (S) * BK + (sg_ << 2);\
            float* dst_ = lds + ((S) & 3) * 4096 + rp_ * 128;                    \
            __builtin_amdgcn_global_load_lds(                                    \
                (const __attribute__((address_space(1))) void*)src_,             \
                (__attribute__((address_space(3))) void*)dst_, 16, 0, 0);        \
        } } while (0)

    // raw W loads for step S (chunk C = S*8+kg): 4 VMEM ops, double-buffered
#define WLD(S) do {                                                              \
        const float* w0_ = wbase + ((S) * 8 + kg) * 16;                          \
        ws[(S) & 1][0] = *(const float4*)(w0_);                                  \
        ws[(S) & 1][1] = *(const float4*)(w0_ + 4);                              \
        ws[(S) & 1][2] = *(const float4*)(w0_ + 32 * DIM);                       \
        ws[(S) & 1][3] = *(const float4*)(w0_ + 32 * DIM + 4);                   \
    } while (0)

    // compute step S: split-f16 convert (x from LDS, W from regs) + 6 MFMAs
#define COMP(S) do {                                                             \
        const char* lb_ = (const char*)lds + ((S) & 3) * 16384;                  \
        float4 xv0_ = *(const float4*)(lb_ + ro0);                               \
        float4 xv1_ = *(const float4*)(lb_ + ro1);                               \
        f16x8 ah_, al_;                                                          \
        {                                                                        \
            const float* p0_ = (const float*)&xv0_;                              \
            const float* p1_ = (const float*)&xv1_;                              \
            _Pragma("unroll")                                                    \
            for (int j_ = 0; j_ < 4; ++j_) {                                     \
                _Float16 h1_ = (_Float16)p0_[j_];                                \
                ah_[j_] = h1_; al_[j_] = (_Float16)(p0_[j_] - (float)h1_);       \
                _Float16 h2_ = (_Float16)p1_[j_];                                \
                ah_[4 + j_] = h2_; al_[4 + j_] = (_Float16)(p1_[j_] - (float)h2_);\
            }                                                                    \
        }                                                                        \
        f16x8 b0h_, b0l_, b1h_, b1l_;                                            \
        {                                                                        \
            const float* q0_ = (const float*)&ws[(S) & 1][0];                    \
            const float* q1_ = (const float*)&ws[(S) & 1][2];                    \
            _Pragma("unroll")                                                    \
            for (int j_ = 0; j_ < 4; ++j_) {                                     \
                _Float16 h1_ = (_Float16)q0_[j_];                                \
                b0h_[j_] = h1_; b0l_[j_] = (_Float16)(q0_[j_] - (float)h1_);     \
                _Float16 h2_ = (_Float16)q0_[4 + j_];                            \
                b0h_[4 + j_] = h2_; b0l_[4 + j_] = (_Float16)(q0_[4 + j_] - (float)h2_);\
                _Float16 h3_ = (_Float16)q1_[j_];                                \
                b1h_[j_] = h3_; b1l_[j_] = (_Float16)(q1_[j_] - (float)h3_);     \
                _Float16 h4_ = (_Float16)q1_[4 + j_];                            \
                b1h_[4 + j_] = h4_; b1l_[4 + j_] = (_Float16)(q1_[4 + j_] - (float)h4_);\
            }                                                                    \
        }                                                                        \
        acc0 = __builtin_amdgcn_mfma_f32_32x32x16_f16(ah_, b0h_, acc0, 0, 0, 0); \
        acc1 = __builtin_amdgcn_mfma_f32_32x32x16_f16(ah_, b1h_, acc1, 0, 0, 0); \
        acc0 = __builtin_amdgcn_mfma_f32_32x32x16_f16(ah_, b0l_, acc0, 0, 0, 0); \
        acc1 = __builtin_amdgcn_mfma_f32_32x32x16_f16(ah_, b1l_, acc1, 0, 0, 0); \
        acc0 = __builtin_amdgcn_mfma_f32_32x32x16_f16(al_, b0h_, acc0, 0, 0, 0); \
        acc1 = __builtin_amdgcn_mfma_f32_32x32x16_f16(al_, b1h_, acc1, 0, 0, 0); \
    } while (0)

    // step: issue next-chunk W loads + stage(s+3), compute s, counted wait + barrier
#define STEP(S, VMC) do {                                                        \
        WLD((S) + 1);                                                            \
        if ((S) + 3 < NSTEP) STAGE((S) + 3);                                     \
        COMP(S);                                                                 \
        asm volatile("s_waitcnt vmcnt(" VMC ")" ::: "memory");                   \
        __builtin_amdgcn_s_barrier();                                            \
    } while (0)

    // ---- prologue: order pinned so vmcnt(8) waits exactly for stage(0) ----
    STAGE(0);
    asm volatile("" ::: "memory");
    WLD(0);
    asm volatile("" ::: "memory");
    STAGE(1);
    STAGE(2);
    asm volatile("s_waitcnt vmcnt(8)" ::: "memory");   // st0 done; wld0+st1+st2 in flight
    __builtin_amdgcn_s_barrier();

    // ---- main loop, fully unrolled: counted vmcnt keeps 3 stage-steps in flight ----
    STEP(0, "8");  STEP(1, "8");  STEP(2, "8");  STEP(3, "8");
    STEP(4, "8");  STEP(5, "8");  STEP(6, "8");  STEP(7, "8");
    STEP(8, "8");  STEP(9, "8");  STEP(10, "8"); STEP(11, "8");
    STEP(12, "8");
    STEP(13, "6");                 // no stage(16): only stage(15)+wld(14) remain
    STEP(14, "4");                 // only wld(15) remains
    COMP(15);
    __syncthreads();               // full drain before LDS overlay

#undef STEP
#undef COMP
#undef WLD
#undef STAGE

    // ---- partials -> LDS zone kg (row-major 32 x 64); overlays stage buffers ----
    float* zone = lds + kg * (TB * NE);
    #pragma unroll
    for (int r = 0; r < 16; ++r) {
        const int row = (r & 3) + 8 * (r >> 2) + 4 * ko;   // C/D layout (verified)
        zone[row * 64 + m]      = acc0[r];
        zone[row * 64 + 32 + m] = acc1[r];
    }
    __syncthreads();

    // ---- block-wide reduce of 8 zones + bias; logits to global; stage for top-2 ----
    float* logits_out = out + (size_t)TOKENS * 4;
    {
        const int row = tid >> 4;          // 0..31
        const int c4  = (tid & 15) * 4;    // col start (one float4 per thread)
        const int base = row * 64 + c4;
        float4 s0 = *(float4*)&lds[base];
        #pragma unroll
        for (int z = 1; z < KG; ++z) {
            float4 a0 = *(float4*)&lds[z * 2048 + base];
            s0.x += a0.x; s0.y += a0.y; s0.z += a0.z; s0.w += a0.w;
        }
        float4 bv0 = *(const float4*)&b[c4];
        s0.x += bv0.x; s0.y += bv0.y; s0.z += bv0.z; s0.w += bv0.w;
        *(float4*)&lds[base] = s0;     // zone0 in-place (safe: same thread's slot)
        *(float4*)&logits_out[(size_t)(t0 + row) * 64 + c4] = s0;
    }
    __syncthreads();

    // ---- top-2 + softmax: wave kg handles tokens kg*4 .. kg*4+3 ----
    float* idxf = out + (size_t)TOKENS * 2;
    for (int i = 0; i < 4; ++i) {
        const int t = kg * 4 + i;
        const float v = lds[t * 64 + lane];

        float v1 = v; int i1 = lane;
        #pragma unroll
        for (int off = 32; off >= 1; off >>= 1) {
            float ov = __shfl_xor(v1, off, 64);
            int   oi = __shfl_xor(i1, off, 64);
            if (ov > v1 || (ov == v1 && oi < i1)) { v1 = ov; i1 = oi; }
        }
        float vm = (lane == i1) ? -INFINITY : v;
        float v2 = vm; int i2 = lane;
        #pragma unroll
        for (int off = 32; off >= 1; off >>= 1) {
            float ov = __shfl_xor(v2, off, 64);
            int   oi = __shfl_xor(i2, off, 64);
            if (ov > v2 || (ov == v2 && oi < i2)) { v2 = ov; i2 = oi; }
        }

        if (lane == 0) {
            const int tok = t0 + t;
            float e1 = expf(v2 - v1);          // v1 >= v2: stable
            float sden = 1.0f + e1;
            *(float2*)&out[(size_t)tok * 2]  = make_float2(1.0f / sden, e1 / sden);
            *(float2*)&idxf[(size_t)tok * 2] = make_float2((float)i1, (float)i2);
        }
    }
}

extern "C" void kernel_launch(void* const* d_in, const int* in_sizes, int n_in,
                              void* d_out, int out_size, void* d_ws, size_t ws_size,
                              hipStream_t stream) {
    const float* x = (const float*)d_in[0];
    const float* W = (const float*)d_in[1];
    const float* b = (const float*)d_in[2];
    float* out = (float*)d_out;
    (void)d_ws; (void)ws_size;   // workspace no longer used (wpack folded into router)

    router_kernel<<<TOKENS / TB, 512, 0, stream>>>(x, W, b, out);
}

// Round 9
// 204.461 us; speedup vs baseline: 1.0264x; 1.0264x over previous
//
#include <hip/hip_runtime.h>
#include <math.h>

#define TOKENS 16384
#define DIM    2048
#define NE     64
#define TB     32            // tokens per block (one 32-row MFMA tile)
#define KG     8             // k-split across the block's 8 waves
#define BK     128           // k staged per step (32 rows x 128 f32 = 16 KB buffer)
#define NSTEP  (DIM / BK)    // 16 steps; per wave per step: 1 chunk of 16 k

typedef _Float16 f16x8 __attribute__((ext_vector_type(8)));
typedef float    f32x16 __attribute__((ext_vector_type(16)));

// ---------- Kernel A: pack W fp32 -> split-f16 B-fragment layout ----------
// Restored after R8's fold regressed (+16 us router): raw per-lane W loads
// scatter 64x16B granules over 32 rows -> ~8x the L2 transactions of this
// packed layout. Packing once (coalesced both sides) is the right trade.
__global__ __launch_bounds__(256) void wpack_kernel(const float* __restrict__ W,
                                                    _Float16* __restrict__ wp) {
    const int g  = blockIdx.x * 256 + threadIdx.x;   // 16384 threads
    const int c  = g >> 7;
    const int eg = (g >> 6) & 1;
    const int l  = g & 63;
    const int e  = eg * 32 + (l & 31);
    const int k0 = c * 16 + (l >> 5) * 8;
    const float* src = W + (size_t)e * DIM + k0;
    float4 a = *(const float4*)src;
    float4 bq = *(const float4*)(src + 4);
    const float* pa = (const float*)&a;
    const float* pb = (const float*)&bq;
    f16x8 h, lo;
    #pragma unroll
    for (int j = 0; j < 4; ++j) {
        _Float16 h1 = (_Float16)pa[j];
        h[j] = h1; lo[j] = (_Float16)(pa[j] - (float)h1);
        _Float16 h2 = (_Float16)pb[j];
        h[4 + j] = h2; lo[4 + j] = (_Float16)(pb[j] - (float)h2);
    }
    _Float16* dst = wp + ((size_t)(c * 2 + eg) * 2) * 512 + l * 8;
    *(f16x8*)dst = h;
    *(f16x8*)(dst + 512) = lo;
}

// ---------- Kernel B: deep-pipelined LDS-staged split-f16 MFMA GEMM ----------
// R9 change: x staging loads are NON-TEMPORAL (aux=2 -> NT/SLC cpol).
// Theory: the read-once x stream allocates ~1 MB/step/XCD of dead L2 lines,
// evicting the 1 MB wp fragment table between its periodic re-sweeps ->
// ~100+ MB of wp re-fetch falls through to HBM (explains router at ~39 us vs
// 22 us mandatory-byte floor, and why occupancy/coalescing/pipelining/phase
// fixes were all null: the waste is cache-policy-side, not request-side).
// NT keeps x evict-first so wp stays L2-resident; wp loads remain cached.
// Structure = verified R3: 4 stage bufs, depth-3 prefetch, counted vmcnt,
// raw s_barrier, swizzled staging (slot = g ^ (row&7)) on both sides.
__global__ __launch_bounds__(512, 4) void router_kernel(const float* __restrict__ x,
                                                        const _Float16* __restrict__ wp,
                                                        const float* __restrict__ b,
                                                        float* __restrict__ out) {
    __shared__ __align__(16) float lds[16384];   // 64 KB: 4x16KB stage bufs, reused as 8 zones

    const int tid  = threadIdx.x;
    const int kg   = tid >> 6;
    const int lane = tid & 63;
    const int t0   = blockIdx.x * TB;
    const int m    = lane & 31;        // token row within tile (frag row)
    const int ko   = lane >> 5;        // k-octet half

    const float* xbase = x + (size_t)t0 * DIM;
    const _Float16* wpl = wp + lane * 8;

    f32x16 acc0, acc1;
    #pragma unroll
    for (int i = 0; i < 16; ++i) { acc0[i] = 0.0f; acc1[i] = 0.0f; }

    f16x8 bs[2][4];

    // swizzled ds_read byte offsets within a 16KB buffer (constant across steps)
    const int gq  = kg * 4 + ko * 2;
    const int ro0 = m * 512 + (((gq + 0) ^ (m & 7)) << 4);
    const int ro1 = m * 512 + (((gq + 1) ^ (m & 7)) << 4);

    // stage step S: wave kg stages rows 4kg..4kg+3 (2 instrs, 2 rows = 1KB each)
    // aux=2: non-temporal (x is read-once; don't let it thrash wp out of L2)
#define STAGE(S) do {                                                            \
        _Pragma("unroll")                                                        \
        for (int i_ = 0; i_ < 2; ++i_) {                                         \
            const int rp_ = 4 * kg + 2 * i_;                                     \
            const int r_  = rp_ + (lane >> 5);                                   \
            const int sg_ = (lane & 31) ^ (r_ & 7);                              \
            const float* src_ = xbase + (size_t)r_ * DIM + (S) * BK + (sg_ << 2);\
            float* dst_ = lds + ((S) & 3) * 4096 + rp_ * 128;                    \
            __builtin_amdgcn_global_load_lds(                                    \
                (const __attribute__((address_space(1))) void*)src_,             \
                (__attribute__((address_space(3))) void*)dst_, 16, 0, 2);        \
        } } while (0)

    // wp fragment loads for step S (chunk C = S*8+kg), double-buffered by parity
#define WLD(S) do {                                                              \
        const _Float16* wb_ = wpl + (size_t)((S) * 8 + kg) * 2048;               \
        bs[(S) & 1][0] = *(const f16x8*)(wb_);                                   \
        bs[(S) & 1][1] = *(const f16x8*)(wb_ + 512);                             \
        bs[(S) & 1][2] = *(const f16x8*)(wb_ + 1024);                            \
        bs[(S) & 1][3] = *(const f16x8*)(wb_ + 1536);                            \
    } while (0)

    // compute step S: 1 chunk = split-f16 convert + 6 MFMAs
#define COMP(S) do {                                                             \
        const char* lb_ = (const char*)lds + ((S) & 3) * 16384;                  \
        float4 xv0_ = *(const float4*)(lb_ + ro0);                               \
        float4 xv1_ = *(const float4*)(lb_ + ro1);                               \
        f16x8 ah_, al_;                                                          \
        const float* p0_ = (const float*)&xv0_;                                  \
        const float* p1_ = (const float*)&xv1_;                                  \
        _Pragma("unroll")                                                        \
        for (int j_ = 0; j_ < 4; ++j_) {                                         \
            _Float16 h1_ = (_Float16)p0_[j_];                                    \
            ah_[j_] = h1_; al_[j_] = (_Float16)(p0_[j_] - (float)h1_);           \
            _Float16 h2_ = (_Float16)p1_[j_];                                    \
            ah_[4 + j_] = h2_; al_[4 + j_] = (_Float16)(p1_[j_] - (float)h2_);   \
        }                                                                        \
        acc0 = __builtin_amdgcn_mfma_f32_32x32x16_f16(ah_, bs[(S)&1][0], acc0, 0, 0, 0); \
        acc1 = __builtin_amdgcn_mfma_f32_32x32x16_f16(ah_, bs[(S)&1][2], acc1, 0, 0, 0); \
        acc0 = __builtin_amdgcn_mfma_f32_32x32x16_f16(ah_, bs[(S)&1][1], acc0, 0, 0, 0); \
        acc1 = __builtin_amdgcn_mfma_f32_32x32x16_f16(ah_, bs[(S)&1][3], acc1, 0, 0, 0); \
        acc0 = __builtin_amdgcn_mfma_f32_32x32x16_f16(al_, bs[(S)&1][0], acc0, 0, 0, 0); \
        acc1 = __builtin_amdgcn_mfma_f32_32x32x16_f16(al_, bs[(S)&1][2], acc1, 0, 0, 0); \
    } while (0)

    // step: issue next-chunk wp loads + stage(s+3), compute s, counted wait + barrier
#define STEP(S, VMC) do {                                                        \
        WLD((S) + 1);                                                            \
        if ((S) + 3 < NSTEP) STAGE((S) + 3);                                     \
        COMP(S);                                                                 \
        asm volatile("s_waitcnt vmcnt(" VMC ")" ::: "memory");                   \
        __builtin_amdgcn_s_barrier();                                            \
    } while (0)

    // ---- prologue: order pinned so vmcnt(8) waits exactly for stage(0) ----
    STAGE(0);
    asm volatile("" ::: "memory");
    WLD(0);
    asm volatile("" ::: "memory");
    STAGE(1);
    STAGE(2);
    asm volatile("s_waitcnt vmcnt(8)" ::: "memory");   // st0 done; wld0+st1+st2 in flight
    __builtin_amdgcn_s_barrier();

    // ---- main loop, fully unrolled: counted vmcnt keeps 3 stage-steps in flight ----
    STEP(0, "8");  STEP(1, "8");  STEP(2, "8");  STEP(3, "8");
    STEP(4, "8");  STEP(5, "8");  STEP(6, "8");  STEP(7, "8");
    STEP(8, "8");  STEP(9, "8");  STEP(10, "8"); STEP(11, "8");
    STEP(12, "8");
    STEP(13, "6");                 // no stage(16): only stage(15)+wld(14) remain
    STEP(14, "4");                 // only wld(15) remains
    COMP(15);
    __syncthreads();               // full drain before LDS overlay

#undef STEP
#undef COMP
#undef WLD
#undef STAGE

    // ---- partials -> LDS zone kg (row-major 32 x 64); overlays stage buffers ----
    float* zone = lds + kg * (TB * NE);
    #pragma unroll
    for (int r = 0; r < 16; ++r) {
        const int row = (r & 3) + 8 * (r >> 2) + 4 * ko;   // C/D layout (verified)
        zone[row * 64 + m]      = acc0[r];
        zone[row * 64 + 32 + m] = acc1[r];
    }
    __syncthreads();

    // ---- block-wide reduce of 8 zones + bias; logits to global; stage for top-2 ----
    float* logits_out = out + (size_t)TOKENS * 4;
    {
        const int row = tid >> 4;          // 0..31
        const int c4  = (tid & 15) * 4;    // col start (one float4 per thread)
        const int base = row * 64 + c4;
        float4 s0 = *(float4*)&lds[base];
        #pragma unroll
        for (int z = 1; z < KG; ++z) {
            float4 a0 = *(float4*)&lds[z * 2048 + base];
            s0.x += a0.x; s0.y += a0.y; s0.z += a0.z; s0.w += a0.w;
        }
        float4 bv0 = *(const float4*)&b[c4];
        s0.x += bv0.x; s0.y += bv0.y; s0.z += bv0.z; s0.w += bv0.w;
        *(float4*)&lds[base] = s0;     // zone0 in-place (safe: same thread's slot)
        *(float4*)&logits_out[(size_t)(t0 + row) * 64 + c4] = s0;
    }
    __syncthreads();

    // ---- top-2 + softmax: wave kg handles tokens kg*4 .. kg*4+3 ----
    float* idxf = out + (size_t)TOKENS * 2;
    for (int i = 0; i < 4; ++i) {
        const int t = kg * 4 + i;
        const float v = lds[t * 64 + lane];

        float v1 = v; int i1 = lane;
        #pragma unroll
        for (int off = 32; off >= 1; off >>= 1) {
            float ov = __shfl_xor(v1, off, 64);
            int   oi = __shfl_xor(i1, off, 64);
            if (ov > v1 || (ov == v1 && oi < i1)) { v1 = ov; i1 = oi; }
        }
        float vm = (lane == i1) ? -INFINITY : v;
        float v2 = vm; int i2 = lane;
        #pragma unroll
        for (int off = 32; off >= 1; off >>= 1) {
            float ov = __shfl_xor(v2, off, 64);
            int   oi = __shfl_xor(i2, off, 64);
            if (ov > v2 || (ov == v2 && oi < i2)) { v2 = ov; i2 = oi; }
        }

        if (lane == 0) {
            const int tok = t0 + t;
            float e1 = expf(v2 - v1);          // v1 >= v2: stable
            float sden = 1.0f + e1;
            *(float2*)&out[(size_t)tok * 2]  = make_float2(1.0f / sden, e1 / sden);
            *(float2*)&idxf[(size_t)tok * 2] = make_float2((float)i1, (float)i2);
        }
    }
}

extern "C" void kernel_launch(void* const* d_in, const int* in_sizes, int n_in,
                              void* d_out, int out_size, void* d_ws, size_t ws_size,
                              hipStream_t stream) {
    const float* x = (const float*)d_in[0];
    const float* W = (const float*)d_in[1];
    const float* b = (const float*)d_in[2];
    float* out = (float*)d_out;
    _Float16* wp = (_Float16*)d_ws;    // 128*2*2*512 f16 = 1 MB packed fragments

    wpack_kernel<<<64, 256, 0, stream>>>(W, wp);
    router_kernel<<<TOKENS / TB, 512, 0, stream>>>(x, wp, b, out);
}

// Round 10
// 197.837 us; speedup vs baseline: 1.0607x; 1.0335x over previous
//
#include <hip/hip_runtime.h>
#include <math.h>

#define TOKENS 16384
#define DIM    2048
#define NE     64
#define TB     32            // tokens per block (one 32-row MFMA tile)
#define KG     8             // k-split across the block's 8 waves
#define BK     128           // k staged per step (32 rows x 128 f32 = 16 KB buffer)
#define NSTEP  (DIM / BK)    // 16 steps; per wave per step: 1 chunk of 16 k

typedef _Float16 f16x8 __attribute__((ext_vector_type(8)));
typedef float    f32x16 __attribute__((ext_vector_type(16)));

// ---------- Kernel A: pack W fp32 -> split-f16 B-fragment layout ----------
// wp layout (f16 units): ((c*2 + eg)*2 + hl)*512 + lane*8 + j
//   c   = k-chunk (16 k), 0..127      eg = expert half (32 experts)
//   hl  = 0 hi / 1 lo residual        lane: e = eg*32+(lane&31), k = c*16+(lane>>5)*8+j
__global__ __launch_bounds__(256) void wpack_kernel(const float* __restrict__ W,
                                                    _Float16* __restrict__ wp) {
    const int g  = blockIdx.x * 256 + threadIdx.x;   // 16384 threads
    const int c  = g >> 7;
    const int eg = (g >> 6) & 1;
    const int l  = g & 63;
    const int e  = eg * 32 + (l & 31);
    const int k0 = c * 16 + (l >> 5) * 8;
    const float* src = W + (size_t)e * DIM + k0;
    float4 a = *(const float4*)src;
    float4 bq = *(const float4*)(src + 4);
    const float* pa = (const float*)&a;
    const float* pb = (const float*)&bq;
    f16x8 h, lo;
    #pragma unroll
    for (int j = 0; j < 4; ++j) {
        _Float16 h1 = (_Float16)pa[j];
        h[j] = h1; lo[j] = (_Float16)(pa[j] - (float)h1);
        _Float16 h2 = (_Float16)pb[j];
        h[4 + j] = h2; lo[4 + j] = (_Float16)(pb[j] - (float)h2);
    }
    _Float16* dst = wp + ((size_t)(c * 2 + eg) * 2) * 512 + l * 8;
    *(f16x8*)dst = h;
    *(f16x8*)(dst + 512) = lo;
}

// ---------- Kernel B: deep-pipelined LDS-staged split-f16 MFMA GEMM ----------
// SESSION-BEST state (measured 198.8 us). Verified-null/negative variations,
// do NOT re-apply: NT staging aux=2 (+5.7), raw-W fold (+11), deeper k-split
// beyond KG=8, bulk-sync staging, per-block phase rotation encoded any other
// way (runtime-index encoding killed containers; this cselect encoding is the
// safe form and measured = rotation-off within noise).
// Structure: 4 stage bufs, depth-3 prefetch, counted vmcnt (never 0 in loop),
// raw s_barrier, global_load_lds w=16 staging with swizzle slot = g ^ (row&7)
// applied on BOTH the pre-swizzled global source and the ds_read offsets.
__global__ __launch_bounds__(512, 4) void router_kernel(const float* __restrict__ x,
                                                        const _Float16* __restrict__ wp,
                                                        const float* __restrict__ b,
                                                        float* __restrict__ out) {
    __shared__ __align__(16) float lds[16384];   // 64 KB: 4x16KB stage bufs, reused as 8 zones

    const int tid  = threadIdx.x;
    const int kg   = tid >> 6;
    const int lane = tid & 63;
    const int t0   = blockIdx.x * TB;
    const int m    = lane & 31;        // token row within tile (frag row)
    const int ko   = lane >> 5;        // k-octet half
    const int phase = blockIdx.x & 15; // per-block k-column rotation (SGPR-uniform)

    // phase-shifted bases; per-step wrap handled by a uniform select
    const float*    xbase = x + (size_t)t0 * DIM + phase * BK;
    const _Float16* wpl   = wp + lane * 8 + (size_t)phase * 8 * 2048;

    f32x16 acc0, acc1;
    #pragma unroll
    for (int i = 0; i < 16; ++i) { acc0[i] = 0.0f; acc1[i] = 0.0f; }

    f16x8 bs[2][4];

    // swizzled ds_read byte offsets within a 16KB buffer (constant across steps)
    const int gq  = kg * 4 + ko * 2;
    const int ro0 = m * 512 + (((gq + 0) ^ (m & 7)) << 4);
    const int ro1 = m * 512 + (((gq + 1) ^ (m & 7)) << 4);

    // stage step S: wave kg stages rows 4kg..4kg+3 (2 instrs, 2 rows = 1KB each)
    // rotated column base = xbase + S*BK, wrapped by -DIM when phase+S >= 16
#define STAGE(S) do {                                                            \
        const float* cb_ = xbase + (S) * BK - ((phase + (S) >= 16) ? DIM : 0);   \
        _Pragma("unroll")                                                        \
        for (int i_ = 0; i_ < 2; ++i_) {                                         \
            const int rp_ = 4 * kg + 2 * i_;                                     \
            const int r_  = rp_ + (lane >> 5);                                   \
            const int sg_ = (lane & 31) ^ (r_ & 7);                              \
            const float* src_ = cb_ + (size_t)r_ * DIM + (sg_ << 2);             \
            float* dst_ = lds + ((S) & 3) * 4096 + rp_ * 128;                    \
            __builtin_amdgcn_global_load_lds(                                    \
                (const __attribute__((address_space(1))) void*)src_,             \
                (__attribute__((address_space(3))) void*)dst_, 16, 0, 0);        \
        } } while (0)

    // wp fragment loads for step S: rotated chunk base, same wrap-select
#define WLD(S) do {                                                              \
        const _Float16* wb_ = wpl + (size_t)(S) * 8 * 2048 + kg * 2048           \
                              - ((phase + (S) >= 16) ? (size_t)16 * 8 * 2048 : 0);\
        bs[(S) & 1][0] = *(const f16x8*)(wb_);                                   \
        bs[(S) & 1][1] = *(const f16x8*)(wb_ + 512);                             \
        bs[(S) & 1][2] = *(const f16x8*)(wb_ + 1024);                            \
        bs[(S) & 1][3] = *(const f16x8*)(wb_ + 1536);                            \
    } while (0)

    // compute step S: 1 chunk = split-f16 convert + 6 MFMAs
#define COMP(S) do {                                                             \
        const char* lb_ = (const char*)lds + ((S) & 3) * 16384;                  \
        float4 xv0_ = *(const float4*)(lb_ + ro0);                               \
        float4 xv1_ = *(const float4*)(lb_ + ro1);                               \
        f16x8 ah_, al_;                                                          \
        const float* p0_ = (const float*)&xv0_;                                  \
        const float* p1_ = (const float*)&xv1_;                                  \
        _Pragma("unroll")                                                        \
        for (int j_ = 0; j_ < 4; ++j_) {                                         \
            _Float16 h1_ = (_Float16)p0_[j_];                                    \
            ah_[j_] = h1_; al_[j_] = (_Float16)(p0_[j_] - (float)h1_);           \
            _Float16 h2_ = (_Float16)p1_[j_];                                    \
            ah_[4 + j_] = h2_; al_[4 + j_] = (_Float16)(p1_[j_] - (float)h2_);   \
        }                                                                        \
        acc0 = __builtin_amdgcn_mfma_f32_32x32x16_f16(ah_, bs[(S)&1][0], acc0, 0, 0, 0); \
        acc1 = __builtin_amdgcn_mfma_f32_32x32x16_f16(ah_, bs[(S)&1][2], acc1, 0, 0, 0); \
        acc0 = __builtin_amdgcn_mfma_f32_32x32x16_f16(ah_, bs[(S)&1][1], acc0, 0, 0, 0); \
        acc1 = __builtin_amdgcn_mfma_f32_32x32x16_f16(ah_, bs[(S)&1][3], acc1, 0, 0, 0); \
        acc0 = __builtin_amdgcn_mfma_f32_32x32x16_f16(al_, bs[(S)&1][0], acc0, 0, 0, 0); \
        acc1 = __builtin_amdgcn_mfma_f32_32x32x16_f16(al_, bs[(S)&1][2], acc1, 0, 0, 0); \
    } while (0)

    // step: issue next-chunk wp loads + stage(s+3), compute s, counted wait + barrier
#define STEP(S, VMC) do {                                                        \
        WLD((S) + 1);                                                            \
        if ((S) + 3 < NSTEP) STAGE((S) + 3);                                     \
        COMP(S);                                                                 \
        asm volatile("s_waitcnt vmcnt(" VMC ")" ::: "memory");                   \
        __builtin_amdgcn_s_barrier();                                            \
    } while (0)

    // ---- prologue: order pinned so vmcnt(8) waits exactly for stage(0) ----
    STAGE(0);
    asm volatile("" ::: "memory");
    WLD(0);
    asm volatile("" ::: "memory");
    STAGE(1);
    STAGE(2);
    asm volatile("s_waitcnt vmcnt(8)" ::: "memory");   // st0 done; wld0+st1+st2 in flight
    __builtin_amdgcn_s_barrier();

    // ---- main loop, fully unrolled: counted vmcnt keeps 3 stage-steps in flight ----
    STEP(0, "8");  STEP(1, "8");  STEP(2, "8");  STEP(3, "8");
    STEP(4, "8");  STEP(5, "8");  STEP(6, "8");  STEP(7, "8");
    STEP(8, "8");  STEP(9, "8");  STEP(10, "8"); STEP(11, "8");
    STEP(12, "8");
    STEP(13, "6");                 // no stage(16): only stage(15)+wld(14) remain
    STEP(14, "4");                 // only wld(15) remains
    COMP(15);
    __syncthreads();               // full drain before LDS overlay

#undef STEP
#undef COMP
#undef WLD
#undef STAGE

    // ---- partials -> LDS zone kg (row-major 32 x 64); overlays stage buffers ----
    float* zone = lds + kg * (TB * NE);
    #pragma unroll
    for (int r = 0; r < 16; ++r) {
        const int row = (r & 3) + 8 * (r >> 2) + 4 * ko;   // C/D layout (verified)
        zone[row * 64 + m]      = acc0[r];
        zone[row * 64 + 32 + m] = acc1[r];
    }
    __syncthreads();

    // ---- block-wide reduce of 8 zones + bias; logits to global; stage for top-2 ----
    float* logits_out = out + (size_t)TOKENS * 4;
    {
        const int row = tid >> 4;          // 0..31
        const int c4  = (tid & 15) * 4;    // col start (one float4 per thread)
        const int base = row * 64 + c4;
        float4 s0 = *(float4*)&lds[base];
        #pragma unroll
        for (int z = 1; z < KG; ++z) {
            float4 a0 = *(float4*)&lds[z * 2048 + base];
            s0.x += a0.x; s0.y += a0.y; s0.z += a0.z; s0.w += a0.w;
        }
        float4 bv0 = *(const float4*)&b[c4];
        s0.x += bv0.x; s0.y += bv0.y; s0.z += bv0.z; s0.w += bv0.w;
        *(float4*)&lds[base] = s0;     // zone0 in-place (safe: same thread's slot)
        *(float4*)&logits_out[(size_t)(t0 + row) * 64 + c4] = s0;
    }
    __syncthreads();

    // ---- top-2 + softmax: wave kg handles tokens kg*4 .. kg*4+3 ----
    float* idxf = out + (size_t)TOKENS * 2;
    for (int i = 0; i < 4; ++i) {
        const int t = kg * 4 + i;
        const float v = lds[t * 64 + lane];

        float v1 = v; int i1 = lane;
        #pragma unroll
        for (int off = 32; off >= 1; off >>= 1) {
            float ov = __shfl_xor(v1, off, 64);
            int   oi = __shfl_xor(i1, off, 64);
            if (ov > v1 || (ov == v1 && oi < i1)) { v1 = ov; i1 = oi; }
        }
        float vm = (lane == i1) ? -INFINITY : v;
        float v2 = vm; int i2 = lane;
        #pragma unroll
        for (int off = 32; off >= 1; off >>= 1) {
            float ov = __shfl_xor(v2, off, 64);
            int   oi = __shfl_xor(i2, off, 64);
            if (ov > v2 || (ov == v2 && oi < i2)) { v2 = ov; i2 = oi; }
        }

        if (lane == 0) {
            const int tok = t0 + t;
            float e1 = expf(v2 - v1);          // v1 >= v2: stable
            float sden = 1.0f + e1;
            *(float2*)&out[(size_t)tok * 2]  = make_float2(1.0f / sden, e1 / sden);
            *(float2*)&idxf[(size_t)tok * 2] = make_float2((float)i1, (float)i2);
        }
    }
}

extern "C" void kernel_launch(void* const* d_in, const int* in_sizes, int n_in,
                              void* d_out, int out_size, void* d_ws, size_t ws_size,
                              hipStream_t stream) {
    const float* x = (const float*)d_in[0];
    const float* W = (const float*)d_in[1];
    const float* b = (const float*)d_in[2];
    float* out = (float*)d_out;
    _Float16* wp = (_Float16*)d_ws;    // 128*2*2*512 f16 = 1 MB packed fragments

    wpack_kernel<<<64, 256, 0, stream>>>(W, wp);
    router_kernel<<<TOKENS / TB, 512, 0, stream>>>(x, wp, b, out);
}